// Round 7
// baseline (81.348 us; speedup 1.0000x reference)
//
#include <hip/hip_runtime.h>

#define B_    1024
#define T_    256
#define C_    128
#define LMAX  32
#define NEGV  -1e9f
#define K_    16
#define STR   257   // LDS row stride (floats): bank = (slot + t) % 32 -> conflict-free

__device__ __forceinline__ float laddexp(float p, float q) {
    float m = fmaxf(p, q);
    float d = fabsf(p - q);
    return m + __logf(1.0f + __expf(-d));
}
__device__ __forceinline__ float dpp_shr1(float v) {
    int r = __builtin_amdgcn_update_dpp(__float_as_int(NEGV), __float_as_int(v),
                                        0x138, 0xF, 0xF, false);   // wave_shr:1
    return __int_as_float(r);
}
template<int CTRL>
__device__ __forceinline__ float dpp_mov0(float v) {
    return __int_as_float(__builtin_amdgcn_update_dpp(0, __float_as_int(v),
                                                      CTRL, 0xF, 0xF, true));
}
__device__ __forceinline__ float readlanef(float v, int l) {
    return __int_as_float(__builtin_amdgcn_readlane(__float_as_int(v), l));
}
__device__ __forceinline__ float readlane0f(float v) {
    return __int_as_float(__builtin_amdgcn_readfirstlane(__float_as_int(v)));
}

// per-32-half sum: after this, lane31 = sum(l0..31), lane63 = sum(l32..63)
__device__ __forceinline__ float halfsum_dpp(float v) {
    v += dpp_mov0<0x111>(v);   // row_shr:1
    v += dpp_mov0<0x112>(v);   // row_shr:2
    v += dpp_mov0<0x114>(v);   // row_shr:4
    v += dpp_mov0<0x118>(v);   // row_shr:8
    v += dpp_mov0<0x142>(v);   // row_bcast:15
    return v;
}
__device__ __forceinline__ float halfsum_shfl(float v) {
    #pragma unroll
    for (int off = 16; off; off >>= 1) v += __shfl_xor(v, off);  // stays in 32-half
    return v;
}

template<bool DPP>
__device__ __forceinline__ void ctc_step(float& a, float& a64, float lp,
                                         int lane, bool skip) {
    float am1, am2;
    if constexpr (DPP) {
        am1 = dpp_shr1(a);
        am2 = dpp_shr1(am1);
    } else {
        float s1 = __shfl_up(a, 1);
        float s2 = __shfl_up(a, 2);
        am1 = (lane < 1) ? NEGV : s1;
        am2 = (lane < 2) ? NEGV : s2;
    }
    float a63  = readlanef(a, 63);
    float am2e = skip ? am2 : NEGV;
    float m    = fmaxf(fmaxf(a, am1), am2e);
    float r    = m + __logf(__expf(a - m) + __expf(am1 - m) + __expf(am2e - m));
    float lpb  = readlane0f(lp);
    float m2   = fmaxf(a64, a63);
    float r64  = m2 + __logf(__expf(a64 - m2) + __expf(a63 - m2));
    a   = r + lp;
    a64 = r64 + lpb;
}

// phase-2 body: stride-1 reads from LDS base (per-lane slot row)
template<bool DPP>
__device__ __forceinline__ float ctc_body_l(const float* __restrict__ gb,
                                            int lane, bool skip, int L) {
    float xA[K_], xB[K_];
    #pragma unroll
    for (int k = 0; k < K_; ++k) xA[k] = gb[k];
    #pragma unroll
    for (int k = 0; k < K_; ++k) xB[k] = gb[K_ + k];

    float a   = (lane == 0 || (lane == 1 && L > 0)) ? xA[0] : NEGV;
    float a64 = NEGV;
    #pragma unroll
    for (int k = 1; k < K_; ++k) ctc_step<DPP>(a, a64, xA[k], lane, skip);

    for (int c = 1; c <= 13; c += 2) {
        const float* pa = gb + (c + 1) * K_;
        #pragma unroll
        for (int k = 0; k < K_; ++k) xA[k] = pa[k];
        #pragma unroll
        for (int k = 0; k < K_; ++k) ctc_step<DPP>(a, a64, xB[k], lane, skip);
        const float* pb = gb + (c + 2) * K_;
        #pragma unroll
        for (int k = 0; k < K_; ++k) xB[k] = pb[k];
        #pragma unroll
        for (int k = 0; k < K_; ++k) ctc_step<DPP>(a, a64, xA[k], lane, skip);
    }
    #pragma unroll
    for (int k = 0; k < K_; ++k) ctc_step<DPP>(a, a64, xB[k], lane, skip);

    int idx_last  = 2 * L;
    float a_blank = (idx_last >= 64) ? a64 : __shfl(a, idx_last);
    int il        = idx_last - 1; if (il < 0) il = 0;
    float a_label = __shfl(a, il);
    if (L == 0) a_label = NEGV;
    return -laddexp(a_blank, a_label);
}

// ---------------------------------------------------------------------------
// Fused kernel: one block per example.
// Phase 1: each wave streams 64 contiguous rows with float4 loads (2 rows per
// wave-load), 8-deep register double-buffer; per-half-wave lse; 4-shfl gather
// serves both rows; fp32 results -> LDS.
// Phase 2: wave 0 runs the log-domain recurrence from LDS.
// ---------------------------------------------------------------------------
__global__ void __launch_bounds__(256, 4) fused_kernel(const float* __restrict__ yp,
                                                       const int* __restrict__ yt,
                                                       float* __restrict__ loss) {
    __shared__ float lp[33 * STR];   // 33,924 B
    int tid  = threadIdx.x;
    int wave = tid >> 6;
    int lane = tid & 63;
    int b    = blockIdx.x;

    // runtime DPP probes (wave-uniform; shfl fallback on failure)
    int probe  = __builtin_amdgcn_update_dpp(-1, lane, 0x138, 0xF, 0xF, false);
    bool shrok = __all(probe == ((lane == 0) ? -1 : lane - 1)) != 0;
    float ptst = halfsum_dpp((float)(lane + 1));
    bool sumok = __all(readlanef(ptst, 31) == 528.0f &&
                       readlanef(ptst, 63) == 1552.0f) != 0;

    // labels (same 32 for the whole block)
    int cj = yt[b * LMAX + (lane & 31)];
    cj = min(max(cj, 0), C_ - 1);
    int myc   = cj;                         // class this lane gathers (both halves)
    int srcl4 = (myc >> 2) | (lane & 32);   // source lane for its float4

    const float4* src = (const float4*)(yp + (size_t)b * T_ * C_) + wave * 2048 + lane;

    float4 A[8], Bv[8];
    #define LD(BUF, CI) do { _Pragma("unroll")                                \
        for (int j = 0; j < 8; ++j) BUF[j] = src[((CI) * 8 + j) * 64]; } while (0)

    #define PROC(BUF, CI) do { _Pragma("unroll")                              \
        for (int j = 0; j < 8; ++j) {                                         \
            float4 v = BUF[j];                                                \
            float e = __expf(fminf(v.x, 80.f)) + __expf(fminf(v.y, 80.f))     \
                    + __expf(fminf(v.z, 80.f)) + __expf(fminf(v.w, 80.f));    \
            float t = sumok ? halfsum_dpp(e) : halfsum_shfl(e);               \
            float s31 = readlanef(t, 31), s63 = readlanef(t, 63);             \
            float lsev = __logf((lane < 32) ? s31 : s63);                     \
            float g0 = __shfl(v.x, srcl4);                                    \
            float g1 = __shfl(v.y, srcl4);                                    \
            float g2 = __shfl(v.z, srcl4);                                    \
            float g3 = __shfl(v.w, srcl4);                                    \
            float s01 = (myc & 1) ? g1 : g0;                                  \
            float s23 = (myc & 1) ? g3 : g2;                                  \
            float xv  = (myc & 2) ? s23 : s01;                                \
            int r0 = wave * 64 + ((CI) * 8 + j) * 2;                          \
            int r  = r0 + (lane >> 5);                                        \
            lp[((lane & 31) + 1) * STR + r] = xv - lsev;                      \
            float bw0 = readlanef(v.w, 31);                                   \
            float bw1 = readlanef(v.w, 63);                                   \
            if ((lane & 31) == 0)                                             \
                lp[r] = ((lane < 32) ? bw0 : bw1) - lsev;                     \
        } } while (0)

    LD(A, 0); LD(Bv, 1);
    PROC(A, 0); LD(A, 2);
    PROC(Bv, 1); LD(Bv, 3);
    PROC(A, 2);
    PROC(Bv, 3);
    #undef LD
    #undef PROC

    __syncthreads();
    if (wave != 0) return;

    // phase 2: wave 0 only
    const int* lab = yt + b * LMAX;
    int myl = (lane < LMAX) ? lab[lane] : 99;
    unsigned long long bal = __ballot(lane < LMAX && myl != 99);
    int L = __popcll(bal);

    int  j2     = lane >> 1;
    int  labj   = lab[j2 & (LMAX - 1)];
    int  labjm1 = (j2 > 0) ? lab[j2 - 1] : (C_ - 1);
    bool odd    = (lane & 1) != 0;
    bool skip   = odd && (labj != labjm1);
    int  myslot = odd ? (1 + j2) : 0;
    const float* lpb = &lp[myslot * STR];

    float lb = shrok ? ctc_body_l<true >(lpb, lane, skip, L)
                     : ctc_body_l<false>(lpb, lane, skip, L);
    if (lane == 0) loss[b] = lb;
}

// ---------------------------------------------------------------------------
// mean of per-example losses -> d_out[0]
// ---------------------------------------------------------------------------
__global__ void __launch_bounds__(256) reduce_kernel(const float* __restrict__ loss,
                                                     float* __restrict__ out) {
    __shared__ float ps[4];
    int t = threadIdx.x;
    float4 v = ((const float4*)loss)[t];
    float s = v.x + v.y + v.z + v.w;
    #pragma unroll
    for (int off = 32; off; off >>= 1) s += __shfl_xor(s, off);
    if ((t & 63) == 0) ps[t >> 6] = s;
    __syncthreads();
    if (t == 0) out[0] = (ps[0] + ps[1] + ps[2] + ps[3]) * (1.0f / B_);
}

extern "C" void kernel_launch(void* const* d_in, const int* in_sizes, int n_in,
                              void* d_out, int out_size, void* d_ws, size_t ws_size,
                              hipStream_t stream) {
    const int*   yt  = (const int*)d_in[0];
    const float* yp  = (const float*)d_in[1];
    float*       out = (float*)d_out;
    float*       loss = (float*)d_ws;          // [B] floats

    fused_kernel<<<B_, 256, 0, stream>>>(yp, yt, loss);
    reduce_kernel<<<1, 256, 0, stream>>>(loss, out);
}

// Round 8
// 65.919 us; speedup vs baseline: 1.2341x; 1.2341x over previous
//
#include <hip/hip_runtime.h>
#include <hip/hip_fp16.h>

#define B_    1024
#define T_    256
#define C_    128
#define LMAX  32
#define NEGV  -1e9f
#define K_    16
#define STRH  274   // lp row stride in halves: bank(slot) = 9*slot%32, all distinct

__device__ __forceinline__ float laddexp(float p, float q) {
    float m = fmaxf(p, q);
    float d = fabsf(p - q);
    return m + __logf(1.0f + __expf(-d));
}
__device__ __forceinline__ float dpp_shr1(float v) {
    int r = __builtin_amdgcn_update_dpp(__float_as_int(NEGV), __float_as_int(v),
                                        0x138, 0xF, 0xF, false);   // wave_shr:1
    return __int_as_float(r);
}
template<int CTRL>
__device__ __forceinline__ float dpp_mov0(float v) {
    return __int_as_float(__builtin_amdgcn_update_dpp(0, __float_as_int(v),
                                                      CTRL, 0xF, 0xF, true));
}
__device__ __forceinline__ float readlanef(float v, int l) {
    return __int_as_float(__builtin_amdgcn_readlane(__float_as_int(v), l));
}
__device__ __forceinline__ float readlane0f(float v) {
    return __int_as_float(__builtin_amdgcn_readfirstlane(__float_as_int(v)));
}

// per-32-half sum: lane31 = sum(l0..31), lane63 = sum(l32..63)
__device__ __forceinline__ float halfsum_dpp(float v) {
    v += dpp_mov0<0x111>(v);   // row_shr:1
    v += dpp_mov0<0x112>(v);   // row_shr:2
    v += dpp_mov0<0x114>(v);   // row_shr:4
    v += dpp_mov0<0x118>(v);   // row_shr:8
    v += dpp_mov0<0x142>(v);   // row_bcast:15
    return v;
}
__device__ __forceinline__ float halfsum_shfl(float v) {
    #pragma unroll
    for (int off = 16; off; off >>= 1) v += __shfl_xor(v, off);
    return v;
}

template<bool DPP>
__device__ __forceinline__ void ctc_step(float& a, float& a64, float lp,
                                         int lane, bool skip) {
    float am1, am2;
    if constexpr (DPP) {
        am1 = dpp_shr1(a);
        am2 = dpp_shr1(am1);
    } else {
        float s1 = __shfl_up(a, 1);
        float s2 = __shfl_up(a, 2);
        am1 = (lane < 1) ? NEGV : s1;
        am2 = (lane < 2) ? NEGV : s2;
    }
    float a63  = readlanef(a, 63);
    float am2e = skip ? am2 : NEGV;
    float m    = fmaxf(fmaxf(a, am1), am2e);
    float r    = m + __logf(__expf(a - m) + __expf(am1 - m) + __expf(am2e - m));
    float lpb  = readlane0f(lp);
    float m2   = fmaxf(a64, a63);
    float r64  = m2 + __logf(__expf(a64 - m2) + __expf(a63 - m2));
    a   = r + lp;
    a64 = r64 + lpb;
}

// phase-2 body: stride-1 fp16 reads from LDS (per-lane slot row)
template<bool DPP>
__device__ __forceinline__ float ctc_body_l(const __half* __restrict__ gb,
                                            int lane, bool skip, int L) {
    float xA[K_], xB[K_];
    #pragma unroll
    for (int k = 0; k < K_; ++k) xA[k] = __half2float(gb[k]);
    #pragma unroll
    for (int k = 0; k < K_; ++k) xB[k] = __half2float(gb[K_ + k]);

    float a   = (lane == 0 || (lane == 1 && L > 0)) ? xA[0] : NEGV;
    float a64 = NEGV;
    #pragma unroll
    for (int k = 1; k < K_; ++k) ctc_step<DPP>(a, a64, xA[k], lane, skip);

    for (int c = 1; c <= 13; c += 2) {
        const __half* pa = gb + (c + 1) * K_;
        #pragma unroll
        for (int k = 0; k < K_; ++k) xA[k] = __half2float(pa[k]);
        #pragma unroll
        for (int k = 0; k < K_; ++k) ctc_step<DPP>(a, a64, xB[k], lane, skip);
        const __half* pb = gb + (c + 2) * K_;
        #pragma unroll
        for (int k = 0; k < K_; ++k) xB[k] = __half2float(pb[k]);
        #pragma unroll
        for (int k = 0; k < K_; ++k) ctc_step<DPP>(a, a64, xA[k], lane, skip);
    }
    #pragma unroll
    for (int k = 0; k < K_; ++k) ctc_step<DPP>(a, a64, xB[k], lane, skip);

    int idx_last  = 2 * L;
    float a_blank = (idx_last >= 64) ? a64 : __shfl(a, idx_last);
    int il        = idx_last - 1; if (il < 0) il = 0;
    float a_label = __shfl(a, il);
    if (L == 0) a_label = NEGV;
    return -laddexp(a_blank, a_label);
}

// ---------------------------------------------------------------------------
// Fused kernel, one block (4 waves) per example.
// Phase 1: each wave streams its 64 rows through 4 rotating 1 KB LDS buffers
// filled by global_load_lds (3 chunks in flight, s_waitcnt vmcnt(2) gating —
// no VGPR staging, per-wave counters, no barriers). Per 2-row chunk:
// ds_read_b128, clamp-exp, DPP half-wave sum, 4-shfl gather, fp16 -> lp LDS.
// Phase 2: wave 0 runs the log-domain recurrence from LDS.
// ---------------------------------------------------------------------------
__global__ void __launch_bounds__(256, 4) fused_kernel(const float* __restrict__ yp,
                                                       const int* __restrict__ yt,
                                                       float* __restrict__ loss) {
    __shared__ float  stage[4][4][256];     // 16,384 B: [wave][buf][2 rows]
    __shared__ __half lph[33 * STRH];       // 18,084 B
    int tid  = threadIdx.x;
    int wave = tid >> 6;
    int lane = tid & 63;
    int li   = lane & 31;
    int b    = blockIdx.x;

    // runtime DPP probes (wave-uniform; shfl fallback on failure)
    int probe  = __builtin_amdgcn_update_dpp(-1, lane, 0x138, 0xF, 0xF, false);
    bool shrok = __all(probe == ((lane == 0) ? -1 : lane - 1)) != 0;
    float ptst = halfsum_dpp((float)(lane + 1));
    bool sumok = __all(readlanef(ptst, 31) == 528.0f &&
                       readlanef(ptst, 63) == 1552.0f) != 0;

    // labels (same 32 for the whole block)
    int cj = yt[b * LMAX + li];
    cj = min(max(cj, 0), C_ - 1);
    int myc   = cj;
    int srcl4 = (myc >> 2) | (lane & 32);

    const float* srcb = yp + (size_t)b * T_ * C_ + (size_t)wave * 64 * C_;

    // drain label loads so vmcnt counts only the staging DMAs
    asm volatile("s_waitcnt vmcnt(0)" ::: "memory");

    #define ISSUE(CI, BI)                                                      \
        __builtin_amdgcn_global_load_lds(                                      \
            (const __attribute__((address_space(1))) void*)                    \
                (srcb + (size_t)(CI) * 256 + (size_t)lane * 4),                \
            (__attribute__((address_space(3))) void*)&stage[wave][BI][0],      \
            16, 0, 0)

    ISSUE(0, 0); ISSUE(1, 1); ISSUE(2, 2);

    for (int c = 0; c < 32; ++c) {
        if (c < 30) asm volatile("s_waitcnt vmcnt(2)" ::: "memory");
        else        asm volatile("s_waitcnt vmcnt(0)" ::: "memory");
        __builtin_amdgcn_sched_barrier(0);

        const float4* sb = (const float4*)&stage[wave][c & 3][0];
        float4 v = sb[lane];               // half0: row 2c, half1: row 2c+1
        float e = __expf(fminf(v.x, 80.f)) + __expf(fminf(v.y, 80.f))
                + __expf(fminf(v.z, 80.f)) + __expf(fminf(v.w, 80.f));
        float t = sumok ? halfsum_dpp(e) : halfsum_shfl(e);
        float s31 = readlanef(t, 31), s63 = readlanef(t, 63);
        float lsev = __logf((lane < 32) ? s31 : s63);
        float g0 = __shfl(v.x, srcl4);
        float g1 = __shfl(v.y, srcl4);
        float g2 = __shfl(v.z, srcl4);
        float g3 = __shfl(v.w, srcl4);
        float s01 = (myc & 1) ? g1 : g0;
        float s23 = (myc & 1) ? g3 : g2;
        float xv  = (myc & 2) ? s23 : s01;
        int r = wave * 64 + c * 2 + (lane >> 5);
        lph[(li + 1) * STRH + r] = __float2half_rn(xv - lsev);
        float bw0 = readlanef(v.w, 31);
        float bw1 = readlanef(v.w, 63);
        if (li == 0)
            lph[r] = __float2half_rn(((lane < 32) ? bw0 : bw1) - lsev);

        if (c + 3 < 32) {
            __builtin_amdgcn_sched_barrier(0);
            ISSUE(c + 3, (c + 3) & 3);
        }
    }
    #undef ISSUE

    __syncthreads();
    if (wave != 0) return;

    // phase 2: wave 0 only
    const int* lab = yt + b * LMAX;
    int myl = (lane < LMAX) ? lab[lane] : 99;
    unsigned long long bal = __ballot(lane < LMAX && myl != 99);
    int L = __popcll(bal);

    int  j2     = lane >> 1;
    int  labj   = lab[j2 & (LMAX - 1)];
    int  labjm1 = (j2 > 0) ? lab[j2 - 1] : (C_ - 1);
    bool odd    = (lane & 1) != 0;
    bool skip   = odd && (labj != labjm1);
    int  myslot = odd ? (1 + j2) : 0;
    const __half* gb = &lph[myslot * STRH];

    float lb = shrok ? ctc_body_l<true >(gb, lane, skip, L)
                     : ctc_body_l<false>(gb, lane, skip, L);
    if (lane == 0) loss[b] = lb;
}

// ---------------------------------------------------------------------------
// mean of per-example losses -> d_out[0]
// ---------------------------------------------------------------------------
__global__ void __launch_bounds__(256) reduce_kernel(const float* __restrict__ loss,
                                                     float* __restrict__ out) {
    __shared__ float ps[4];
    int t = threadIdx.x;
    float4 v = ((const float4*)loss)[t];
    float s = v.x + v.y + v.z + v.w;
    #pragma unroll
    for (int off = 32; off; off >>= 1) s += __shfl_xor(s, off);
    if ((t & 63) == 0) ps[t >> 6] = s;
    __syncthreads();
    if (t == 0) out[0] = (ps[0] + ps[1] + ps[2] + ps[3]) * (1.0f / B_);
}

extern "C" void kernel_launch(void* const* d_in, const int* in_sizes, int n_in,
                              void* d_out, int out_size, void* d_ws, size_t ws_size,
                              hipStream_t stream) {
    const int*   yt  = (const int*)d_in[0];
    const float* yp  = (const float*)d_in[1];
    float*       out = (float*)d_out;
    float*       loss = (float*)d_ws;          // [B] floats

    fused_kernel<<<B_, 256, 0, stream>>>(yp, yt, loss);
    reduce_kernel<<<1, 256, 0, stream>>>(loss, out);
}